// Round 2
// baseline (619.135 us; speedup 1.0000x reference)
//
#include <hip/hip_runtime.h>
#include <hip/hip_bf16.h>

#define N_NODES 100000
#define N_EDGES 1600000
#define BCAP    64          // bucket capacity per node (max degree; Poisson(16) tail ~1e-20)
#define EPS     1e-12f

typedef __bf16 bf16x8 __attribute__((ext_vector_type(8)));
typedef float  f32x4  __attribute__((ext_vector_type(4)));

__device__ __forceinline__ unsigned short f2bf(float f){
    union { float f; unsigned int i; } v; v.f = f;
    unsigned int x = v.i;
    return (unsigned short)((x + 0x7fffu + ((x >> 16) & 1u)) >> 16);
}
__device__ __forceinline__ float bfbits2f(unsigned short u){
    union { unsigned int i; float f; } v; v.i = ((unsigned int)u) << 16; return v.f;
}

// ---- K_init: blocks [0,390] zero deg; [391,646] fuse M/dvec; [647,662] W1 tile
__global__ void k_init(int* __restrict__ deg,
                       const float* __restrict__ lin_W,
                       const float* __restrict__ lin_b,
                       const float* __restrict__ conv_W,
                       __bf16* __restrict__ Mbf,
                       float* __restrict__ dvec,
                       const float* __restrict__ asg_W1,
                       __bf16* __restrict__ W1bf){
    int b = blockIdx.x;
    int t = threadIdx.x;
    if (b < 391){
        int i = b * 256 + t;
        if (i < N_NODES) deg[i] = 0;
    } else if (b < 647){
        int id = (b - 391) * 256 + t;             // 0..65535
        int f  = id & 255;
        int o  = id >> 8;                          // k*64+q
        int k  = o >> 6;
        const float* cw = conv_W + o * 64;         // conv_W[k][q][p]
        const float* lw = lin_W + k * 64 * 256 + f;// lin_W[k][p][f]
        float s = 0.f;
        #pragma unroll 8
        for (int p = 0; p < 64; ++p) s += cw[p] * lw[p * 256];
        Mbf[id] = (__bf16)s;
        if (f == 0){
            const float* lb = lin_b + k * 64;
            float d = 0.f;
            for (int p = 0; p < 64; ++p) d += lb[p] * cw[p];
            dvec[o] = d;
        }
    } else {
        int id = (b - 647) * 256 + t;              // 0..4095
        int f  = id & 255;
        int o  = id >> 8;                          // 0..15
        float v = 0.f;
        if (o < 4)      v = asg_W1[o * 512 + f];
        else if (o < 8) v = asg_W1[(o - 4) * 512 + 256 + f];
        W1bf[id] = (__bf16)v;
    }
}

// ---- K_gemm: c[n][o] = bf16(x[n,:].M[o,:] + dvec[o]) via MFMA; proj_a/b via W1 tile
__global__ __launch_bounds__(256) void k_gemm(const float* __restrict__ x,
                                              const __bf16* __restrict__ Mbf,
                                              const __bf16* __restrict__ W1bf,
                                              const float* __restrict__ dvec,
                                              __bf16* __restrict__ c,
                                              float* __restrict__ proj_a,
                                              float* __restrict__ proj_b){
    int lane = threadIdx.x & 63, wv = threadIdx.x >> 6;
    int nb = blockIdx.x * 128 + wv * 32;   // 32 nodes per wave
    int l15 = lane & 15, quad = lane >> 4;
    f32x4 acc[2][16], accp[2];
    #pragma unroll
    for (int mi = 0; mi < 2; ++mi){
        accp[mi] = f32x4{0.f, 0.f, 0.f, 0.f};
        #pragma unroll
        for (int ni = 0; ni < 16; ++ni) acc[mi][ni] = f32x4{0.f, 0.f, 0.f, 0.f};
    }
    const float* xg[2];
    #pragma unroll
    for (int mi = 0; mi < 2; ++mi){
        int row = nb + mi * 16 + l15;
        if (row >= N_NODES) row = N_NODES - 1;   // clamp for tail
        xg[mi] = x + (size_t)row * 256 + quad * 8;
    }
    for (int k0 = 0; k0 < 256; k0 += 32){
        bf16x8 a[2];
        #pragma unroll
        for (int mi = 0; mi < 2; ++mi){
            float4 lo = *(const float4*)(xg[mi] + k0);
            float4 hi = *(const float4*)(xg[mi] + k0 + 4);
            a[mi][0] = (__bf16)lo.x; a[mi][1] = (__bf16)lo.y;
            a[mi][2] = (__bf16)lo.z; a[mi][3] = (__bf16)lo.w;
            a[mi][4] = (__bf16)hi.x; a[mi][5] = (__bf16)hi.y;
            a[mi][6] = (__bf16)hi.z; a[mi][7] = (__bf16)hi.w;
        }
        #pragma unroll
        for (int ni = 0; ni < 16; ++ni){
            bf16x8 b = *(const bf16x8*)(Mbf + (size_t)(ni * 16 + l15) * 256 + k0 + quad * 8);
            acc[0][ni] = __builtin_amdgcn_mfma_f32_16x16x32_bf16(a[0], b, acc[0][ni], 0, 0, 0);
            acc[1][ni] = __builtin_amdgcn_mfma_f32_16x16x32_bf16(a[1], b, acc[1][ni], 0, 0, 0);
        }
        bf16x8 bw = *(const bf16x8*)(W1bf + (size_t)l15 * 256 + k0 + quad * 8);
        accp[0] = __builtin_amdgcn_mfma_f32_16x16x32_bf16(a[0], bw, accp[0], 0, 0, 0);
        accp[1] = __builtin_amdgcn_mfma_f32_16x16x32_bf16(a[1], bw, accp[1], 0, 0, 0);
    }
    #pragma unroll
    for (int ni = 0; ni < 16; ++ni){
        int o = ni * 16 + l15;
        float dv = dvec[o];
        #pragma unroll
        for (int mi = 0; mi < 2; ++mi){
            int nrow = nb + mi * 16 + quad * 4;
            #pragma unroll
            for (int r = 0; r < 4; ++r){
                int node = nrow + r;
                if (node < N_NODES) c[(size_t)node * 256 + o] = (__bf16)(acc[mi][ni][r] + dv);
            }
        }
    }
    if (l15 < 8){
        #pragma unroll
        for (int mi = 0; mi < 2; ++mi){
            int nrow = nb + mi * 16 + quad * 4;
            #pragma unroll
            for (int r = 0; r < 4; ++r){
                int node = nrow + r;
                if (node < N_NODES){
                    float v = accp[mi][r];
                    if (l15 < 4) proj_a[node * 4 + l15] = v;
                    else         proj_b[node * 4 + (l15 - 4)] = v;
                }
            }
        }
    }
}

// ---- K_edge: local dtype detect + softmax gate + bucket scatter {col, w*4 bf16}
__global__ __launch_bounds__(256) void k_edge(const void* __restrict__ row_raw,
                                              const void* __restrict__ col_raw,
                                              const float* __restrict__ proj_a,
                                              const float* __restrict__ proj_b,
                                              const float* __restrict__ asg_b1,
                                              const float* __restrict__ asg_W2,
                                              const float* __restrict__ asg_b2,
                                              int* __restrict__ deg,
                                              int4* __restrict__ bucket){
    __shared__ int s_is64;
    int t = threadIdx.x;
    if (t == 0) s_is64 = 1;
    __syncthreads();
    // sample the first 512 words of both arrays: int64 inputs have all odd words 0
    unsigned v = ((const unsigned*)row_raw)[2 * t + 1] | ((const unsigned*)col_raw)[2 * t + 1];
    if (v) s_is64 = 0;
    __syncthreads();

    int e = blockIdx.x * 256 + t;
    if (e >= N_EDGES) return;
    int r, cl;
    if (s_is64){
        r  = (int)((const long long*)row_raw)[e];
        cl = (int)((const long long*)col_raw)[e];
    } else {
        r  = ((const int*)row_raw)[e];
        cl = ((const int*)col_raw)[e];
    }
    float4 pa = *(const float4*)(proj_a + (size_t)cl * 4);
    float4 pb = *(const float4*)(proj_b + (size_t)r * 4);
    float h1[4];
    h1[0] = pa.x + pb.x + asg_b1[0];
    h1[1] = pa.y + pb.y + asg_b1[1];
    h1[2] = pa.z + pb.z + asg_b1[2];
    h1[3] = pa.w + pb.w + asg_b1[3];
    float h2[4];
    #pragma unroll
    for (int i = 0; i < 4; ++i){
        float s = asg_b2[i];
        #pragma unroll
        for (int j = 0; j < 4; ++j) s += asg_W2[i * 4 + j] * h1[j];
        h2[i] = s;
    }
    float m = fmaxf(fmaxf(h2[0], h2[1]), fmaxf(h2[2], h2[3]));
    float e0 = __expf(h2[0] - m), e1 = __expf(h2[1] - m);
    float e2 = __expf(h2[2] - m), e3 = __expf(h2[3] - m);
    float inv = 1.f / (e0 + e1 + e2 + e3);
    unsigned b0 = f2bf(e0 * inv), b1 = f2bf(e1 * inv);
    unsigned b2 = f2bf(e2 * inv), b3 = f2bf(e3 * inv);
    int4 rec;
    rec.x = cl;
    rec.y = (int)(b0 | (b1 << 16));
    rec.z = (int)(b2 | (b3 << 16));
    rec.w = 0;
    int pos = atomicAdd(&deg[r], 1);
    if (pos < BCAP) bucket[(size_t)r * BCAP + pos] = rec;
}

// ---- K_node: pull-mode segment sum, 8 edge-slots x 32 lanes, 16B gathers
#define RSTR  260   // 256 + 4 pad (words) for slot-partial rows
__global__ __launch_bounds__(256) void k_node(const __bf16* __restrict__ c,
                                              const int* __restrict__ deg,
                                              const int4* __restrict__ bucket,
                                              const float* __restrict__ bias,
                                              const float* __restrict__ cls_W,
                                              const float* __restrict__ cls_b,
                                              float* __restrict__ out_h,
                                              float* __restrict__ out_logits){
    __shared__ int4  s_rec[BCAP];
    __shared__ float s_red[8 * RSTR];
    __shared__ float lred[4][4];

    int n = blockIdx.x;
    int t = threadIdx.x;
    int slot = t >> 5, lane32 = t & 31;
    int k2 = lane32 >> 3;                 // k-group of this lane's 8 features
    int fb = lane32 * 8;                  // feature base (0..248)
    int dn = deg[n]; if (dn > BCAP) dn = BCAP;

    if (t < dn) s_rec[t] = bucket[(size_t)n * BCAP + t];
    __syncthreads();

    float acc[8];
    #pragma unroll
    for (int r = 0; r < 8; ++r) acc[r] = 0.f;

    for (int i = slot; i < dn; i += 8){
        int4 rec = s_rec[i];
        int  ww  = (k2 < 2) ? rec.y : rec.z;
        unsigned short us = (k2 & 1) ? (unsigned short)(ww >> 16)
                                     : (unsigned short)(ww & 0xffff);
        float w = bfbits2f(us);
        bf16x8 v = *(const bf16x8*)(c + (size_t)rec.x * 256 + fb);
        #pragma unroll
        for (int r = 0; r < 8; ++r) acc[r] += w * (float)v[r];
    }
    #pragma unroll
    for (int r = 0; r < 8; ++r) s_red[slot * RSTR + fb + r] = acc[r];
    __syncthreads();

    float a = 0.f;
    #pragma unroll
    for (int s = 0; s < 8; ++s) a += s_red[s * RSTR + t];
    a += bias[t];

    int k = t >> 6, lane = t & 63;
    float ss = a * a;
    #pragma unroll
    for (int off = 32; off; off >>= 1) ss += __shfl_xor(ss, off, 64);
    float nrm = sqrtf(ss);
    float h = a / fmaxf(nrm, EPS);
    out_h[(size_t)n * 256 + t] = h;

    float lj[4];
    #pragma unroll
    for (int jj = 0; jj < 4; ++jj){
        float v = h * cls_W[jj * 256 + t];
        #pragma unroll
        for (int off = 32; off; off >>= 1) v += __shfl_xor(v, off, 64);
        lj[jj] = v;
    }
    if (lane == 0){
        #pragma unroll
        for (int jj = 0; jj < 4; ++jj) lred[k][jj] = lj[jj];
    }
    __syncthreads();
    if (t < 4){
        float s = lred[0][t] + lred[1][t] + lred[2][t] + lred[3][t] + cls_b[t];
        out_logits[(size_t)n * 4 + t] = s;
    }
}

extern "C" void kernel_launch(void* const* d_in, const int* in_sizes, int n_in,
                              void* d_out, int out_size, void* d_ws, size_t ws_size,
                              hipStream_t stream){
    const float* x       = (const float*)d_in[0];
    const void*  row_raw = d_in[1];
    const void*  col_raw = d_in[2];
    const float* asg_W1  = (const float*)d_in[3];
    const float* asg_b1  = (const float*)d_in[4];
    const float* asg_W2  = (const float*)d_in[5];
    const float* asg_b2  = (const float*)d_in[6];
    const float* lin_W   = (const float*)d_in[7];
    const float* lin_b   = (const float*)d_in[8];
    const float* conv_W  = (const float*)d_in[9];
    const float* bias    = (const float*)d_in[10];
    const float* cls_W   = (const float*)d_in[11];
    const float* cls_b   = (const float*)d_in[12];

    char* ws = (char*)d_ws;
    size_t off = 0;
    auto alloc = [&](size_t bytes) -> void* {
        void* p = ws + off;
        off += (bytes + 255) & ~(size_t)255;
        return p;
    };
    __bf16* c      = (__bf16*)alloc((size_t)N_NODES * 256 * 2);       // 51.2 MB
    int4*   bucket = (int4*)alloc((size_t)N_NODES * BCAP * 16);       // 102.4 MB
    float*  proj_a = (float*)alloc((size_t)N_NODES * 4 * 4);
    float*  proj_b = (float*)alloc((size_t)N_NODES * 4 * 4);
    __bf16* Mbf    = (__bf16*)alloc(65536 * 2);
    __bf16* W1bf   = (__bf16*)alloc(4096 * 2);
    float*  dvec   = (float*)alloc(256 * 4);
    int*    deg    = (int*)alloc((size_t)N_NODES * 4);

    float* out_h = (float*)d_out;
    float* out_l = out_h + (size_t)N_NODES * 256;

    hipLaunchKernelGGL(k_init, dim3(663), dim3(256), 0, stream,
                       deg, lin_W, lin_b, conv_W, Mbf, dvec, asg_W1, W1bf);
    hipLaunchKernelGGL(k_gemm, dim3((N_NODES + 127) / 128), dim3(256), 0, stream,
                       x, (const __bf16*)Mbf, (const __bf16*)W1bf, dvec, c, proj_a, proj_b);
    hipLaunchKernelGGL(k_edge, dim3(N_EDGES / 256), dim3(256), 0, stream,
                       row_raw, col_raw, proj_a, proj_b, asg_b1, asg_W2, asg_b2,
                       deg, bucket);
    hipLaunchKernelGGL(k_node, dim3(N_NODES), dim3(256), 0, stream,
                       c, deg, bucket, bias, cls_W, cls_b, out_h, out_l);
}

// Round 3
// 532.487 us; speedup vs baseline: 1.1627x; 1.1627x over previous
//
#include <hip/hip_runtime.h>
#include <hip/hip_bf16.h>

#define N_NODES 100000
#define N_EDGES 1600000
#define BCAP    64          // bucket capacity per node (max degree; Poisson(16) tail ~1e-20)
#define EPS     1e-12f

typedef __bf16 bf16x8 __attribute__((ext_vector_type(8)));
typedef float  f32x4  __attribute__((ext_vector_type(4)));

__device__ __forceinline__ unsigned short f2bf(float f){
    union { float f; unsigned int i; } v; v.f = f;
    unsigned int x = v.i;
    return (unsigned short)((x + 0x7fffu + ((x >> 16) & 1u)) >> 16);
}
__device__ __forceinline__ float bits2f(unsigned int u){
    union { unsigned int i; float f; } v; v.i = u; return v.f;
}

// ---- K_init: blocks [0,390] zero deg; [391,646] fuse M/dvec; [647,662] W1 tile
__global__ void k_init(int* __restrict__ deg,
                       const float* __restrict__ lin_W,
                       const float* __restrict__ lin_b,
                       const float* __restrict__ conv_W,
                       __bf16* __restrict__ Mbf,
                       float* __restrict__ dvec,
                       const float* __restrict__ asg_W1,
                       __bf16* __restrict__ W1bf){
    int b = blockIdx.x;
    int t = threadIdx.x;
    if (b < 391){
        int i = b * 256 + t;
        if (i < N_NODES) deg[i] = 0;
    } else if (b < 647){
        int id = (b - 391) * 256 + t;             // 0..65535
        int f  = id & 255;
        int o  = id >> 8;                          // k*64+q
        int k  = o >> 6;
        const float* cw = conv_W + o * 64;         // conv_W[k][q][p]
        const float* lw = lin_W + k * 64 * 256 + f;// lin_W[k][p][f]
        float s = 0.f;
        #pragma unroll 8
        for (int p = 0; p < 64; ++p) s += cw[p] * lw[p * 256];
        Mbf[id] = (__bf16)s;
        if (f == 0){
            const float* lb = lin_b + k * 64;
            float d = 0.f;
            for (int p = 0; p < 64; ++p) d += lb[p] * cw[p];
            dvec[o] = d;
        }
    } else {
        int id = (b - 647) * 256 + t;              // 0..4095
        int f  = id & 255;
        int o  = id >> 8;                          // 0..15
        float v = 0.f;
        if (o < 4)      v = asg_W1[o * 512 + f];
        else if (o < 8) v = asg_W1[(o - 4) * 512 + 256 + f];
        W1bf[id] = (__bf16)v;
    }
}

// ---- K_gemm: c[n][o] = bf16(x[n,:].M[o,:] + dvec[o]) via MFMA; proj_a/b via W1 tile
__global__ __launch_bounds__(256) void k_gemm(const float* __restrict__ x,
                                              const __bf16* __restrict__ Mbf,
                                              const __bf16* __restrict__ W1bf,
                                              const float* __restrict__ dvec,
                                              __bf16* __restrict__ c,
                                              float* __restrict__ proj_a,
                                              float* __restrict__ proj_b){
    int lane = threadIdx.x & 63, wv = threadIdx.x >> 6;
    int nb = blockIdx.x * 128 + wv * 32;   // 32 nodes per wave
    int l15 = lane & 15, quad = lane >> 4;
    f32x4 acc[2][16], accp[2];
    #pragma unroll
    for (int mi = 0; mi < 2; ++mi){
        accp[mi] = f32x4{0.f, 0.f, 0.f, 0.f};
        #pragma unroll
        for (int ni = 0; ni < 16; ++ni) acc[mi][ni] = f32x4{0.f, 0.f, 0.f, 0.f};
    }
    const float* xg[2];
    #pragma unroll
    for (int mi = 0; mi < 2; ++mi){
        int row = nb + mi * 16 + l15;
        if (row >= N_NODES) row = N_NODES - 1;   // clamp for tail
        xg[mi] = x + (size_t)row * 256 + quad * 8;
    }
    for (int k0 = 0; k0 < 256; k0 += 32){
        bf16x8 a[2];
        #pragma unroll
        for (int mi = 0; mi < 2; ++mi){
            float4 lo = *(const float4*)(xg[mi] + k0);
            float4 hi = *(const float4*)(xg[mi] + k0 + 4);
            a[mi][0] = (__bf16)lo.x; a[mi][1] = (__bf16)lo.y;
            a[mi][2] = (__bf16)lo.z; a[mi][3] = (__bf16)lo.w;
            a[mi][4] = (__bf16)hi.x; a[mi][5] = (__bf16)hi.y;
            a[mi][6] = (__bf16)hi.z; a[mi][7] = (__bf16)hi.w;
        }
        #pragma unroll
        for (int ni = 0; ni < 16; ++ni){
            bf16x8 b = *(const bf16x8*)(Mbf + (size_t)(ni * 16 + l15) * 256 + k0 + quad * 8);
            acc[0][ni] = __builtin_amdgcn_mfma_f32_16x16x32_bf16(a[0], b, acc[0][ni], 0, 0, 0);
            acc[1][ni] = __builtin_amdgcn_mfma_f32_16x16x32_bf16(a[1], b, acc[1][ni], 0, 0, 0);
        }
        bf16x8 bw = *(const bf16x8*)(W1bf + (size_t)l15 * 256 + k0 + quad * 8);
        accp[0] = __builtin_amdgcn_mfma_f32_16x16x32_bf16(a[0], bw, accp[0], 0, 0, 0);
        accp[1] = __builtin_amdgcn_mfma_f32_16x16x32_bf16(a[1], bw, accp[1], 0, 0, 0);
    }
    #pragma unroll
    for (int ni = 0; ni < 16; ++ni){
        int o = ni * 16 + l15;
        float dv = dvec[o];
        #pragma unroll
        for (int mi = 0; mi < 2; ++mi){
            int nrow = nb + mi * 16 + quad * 4;
            #pragma unroll
            for (int r = 0; r < 4; ++r){
                int node = nrow + r;
                if (node < N_NODES) c[(size_t)node * 256 + o] = (__bf16)(acc[mi][ni][r] + dv);
            }
        }
    }
    if (l15 < 8){
        #pragma unroll
        for (int mi = 0; mi < 2; ++mi){
            int nrow = nb + mi * 16 + quad * 4;
            #pragma unroll
            for (int r = 0; r < 4; ++r){
                int node = nrow + r;
                if (node < N_NODES){
                    float v = accp[mi][r];
                    if (l15 < 4) proj_a[node * 4 + l15] = v;
                    else         proj_b[node * 4 + (l15 - 4)] = v;
                }
            }
        }
    }
}

// ---- K_edge: local dtype detect + softmax gate + bucket scatter {col, w*4 bf16}
__global__ __launch_bounds__(256) void k_edge(const void* __restrict__ row_raw,
                                              const void* __restrict__ col_raw,
                                              const float* __restrict__ proj_a,
                                              const float* __restrict__ proj_b,
                                              const float* __restrict__ asg_b1,
                                              const float* __restrict__ asg_W2,
                                              const float* __restrict__ asg_b2,
                                              int* __restrict__ deg,
                                              int4* __restrict__ bucket){
    __shared__ int s_is64;
    int t = threadIdx.x;
    if (t == 0) s_is64 = 1;
    __syncthreads();
    // sample the first 512 words of both arrays: int64 inputs have all odd words 0
    unsigned v = ((const unsigned*)row_raw)[2 * t + 1] | ((const unsigned*)col_raw)[2 * t + 1];
    if (v) s_is64 = 0;
    __syncthreads();

    int e = blockIdx.x * 256 + t;
    if (e >= N_EDGES) return;
    int r, cl;
    if (s_is64){
        r  = (int)((const long long*)row_raw)[e];
        cl = (int)((const long long*)col_raw)[e];
    } else {
        r  = ((const int*)row_raw)[e];
        cl = ((const int*)col_raw)[e];
    }
    float4 pa = *(const float4*)(proj_a + (size_t)cl * 4);
    float4 pb = *(const float4*)(proj_b + (size_t)r * 4);
    float h1[4];
    h1[0] = pa.x + pb.x + asg_b1[0];
    h1[1] = pa.y + pb.y + asg_b1[1];
    h1[2] = pa.z + pb.z + asg_b1[2];
    h1[3] = pa.w + pb.w + asg_b1[3];
    float h2[4];
    #pragma unroll
    for (int i = 0; i < 4; ++i){
        float s = asg_b2[i];
        #pragma unroll
        for (int j = 0; j < 4; ++j) s += asg_W2[i * 4 + j] * h1[j];
        h2[i] = s;
    }
    float m = fmaxf(fmaxf(h2[0], h2[1]), fmaxf(h2[2], h2[3]));
    float e0 = __expf(h2[0] - m), e1 = __expf(h2[1] - m);
    float e2 = __expf(h2[2] - m), e3 = __expf(h2[3] - m);
    float inv = 1.f / (e0 + e1 + e2 + e3);
    unsigned b0 = f2bf(e0 * inv), b1 = f2bf(e1 * inv);
    unsigned b2 = f2bf(e2 * inv), b3 = f2bf(e3 * inv);
    int4 rec;
    rec.x = cl;
    rec.y = (int)(b0 | (b1 << 16));
    rec.z = (int)(b2 | (b3 << 16));
    rec.w = 0;
    int pos = atomicAdd(&deg[r], 1);
    if (pos < BCAP) bucket[(size_t)r * BCAP + pos] = rec;
}

// ---- K_node v2: ONE WAVE PER NODE. Zero barriers, zero LDS.
// Lane l owns features 4l..4l+3 (k-group = l>>4). One edge = one coalesced
// 512B wave-read (8B/lane). Records via wave-uniform (scalar) loads.
// Norm: 4-shuffle reduce within 16-lane group. Logits: one 6-level tree x4.
__global__ __launch_bounds__(256) void k_node(const __bf16* __restrict__ c,
                                              const int* __restrict__ deg,
                                              const int4* __restrict__ bucket,
                                              const float* __restrict__ bias,
                                              const float* __restrict__ cls_W,
                                              const float* __restrict__ cls_b,
                                              float* __restrict__ out_h,
                                              float* __restrict__ out_logits){
    int wv = __builtin_amdgcn_readfirstlane((int)(threadIdx.x >> 6));
    int l  = threadIdx.x & 63;
    int n  = blockIdx.x * 4 + wv;
    int k2 = l >> 4;

    // per-lane constants (L1/L2-resident)
    float4 bi = *(const float4*)(bias  + l * 4);
    float4 w0 = *(const float4*)(cls_W + 0 * 256 + l * 4);
    float4 w1 = *(const float4*)(cls_W + 1 * 256 + l * 4);
    float4 w2 = *(const float4*)(cls_W + 2 * 256 + l * 4);
    float4 w3 = *(const float4*)(cls_W + 3 * 256 + l * 4);

    int dn = deg[n]; if (dn > BCAP) dn = BCAP;
    const int4* rec = bucket + (size_t)n * BCAP;
    const __bf16* cb = c + (size_t)l * 4;

    bool hi2 = (k2 & 2) != 0;    // use rec.z (k=2,3) vs rec.y (k=0,1)
    bool odd = (k2 & 1) != 0;    // use hi16 vs lo16

    float a0 = 0.f, a1 = 0.f, a2 = 0.f, a3 = 0.f;
    #pragma unroll 4
    for (int i = 0; i < dn; ++i){
        int4 rc = rec[i];                         // wave-uniform -> s_load
        int  ww = hi2 ? rc.z : rc.y;
        unsigned wb = odd ? ((unsigned)ww & 0xffff0000u) : ((unsigned)ww << 16);
        float w = bits2f(wb);
        uint2 vv = *(const uint2*)(cb + (size_t)rc.x * 256);   // 8B/lane, 512B/wave
        a0 += w * bits2f(vv.x << 16);
        a1 += w * bits2f(vv.x & 0xffff0000u);
        a2 += w * bits2f(vv.y << 16);
        a3 += w * bits2f(vv.y & 0xffff0000u);
    }
    a0 += bi.x; a1 += bi.y; a2 += bi.z; a3 += bi.w;

    // norm over each 64-feature group = 16 consecutive lanes
    float ss = a0 * a0 + a1 * a1 + a2 * a2 + a3 * a3;
    ss += __shfl_xor(ss, 1);
    ss += __shfl_xor(ss, 2);
    ss += __shfl_xor(ss, 4);
    ss += __shfl_xor(ss, 8);
    float nrm = fmaxf(sqrtf(ss), EPS);
    float h0 = a0 / nrm, h1 = a1 / nrm, h2 = a2 / nrm, h3 = a3 / nrm;
    *(float4*)(out_h + (size_t)n * 256 + l * 4) = make_float4(h0, h1, h2, h3);

    // logits: per-lane partial dot then full-wave butterfly
    float p0 = h0 * w0.x + h1 * w0.y + h2 * w0.z + h3 * w0.w;
    float p1 = h0 * w1.x + h1 * w1.y + h2 * w1.z + h3 * w1.w;
    float p2 = h0 * w2.x + h1 * w2.y + h2 * w2.z + h3 * w2.w;
    float p3 = h0 * w3.x + h1 * w3.y + h2 * w3.z + h3 * w3.w;
    #pragma unroll
    for (int off = 1; off < 64; off <<= 1){
        p0 += __shfl_xor(p0, off);
        p1 += __shfl_xor(p1, off);
        p2 += __shfl_xor(p2, off);
        p3 += __shfl_xor(p3, off);
    }
    if (l == 0){
        float4 lg = make_float4(p0 + cls_b[0], p1 + cls_b[1],
                                p2 + cls_b[2], p3 + cls_b[3]);
        *(float4*)(out_logits + (size_t)n * 4) = lg;
    }
}

extern "C" void kernel_launch(void* const* d_in, const int* in_sizes, int n_in,
                              void* d_out, int out_size, void* d_ws, size_t ws_size,
                              hipStream_t stream){
    const float* x       = (const float*)d_in[0];
    const void*  row_raw = d_in[1];
    const void*  col_raw = d_in[2];
    const float* asg_W1  = (const float*)d_in[3];
    const float* asg_b1  = (const float*)d_in[4];
    const float* asg_W2  = (const float*)d_in[5];
    const float* asg_b2  = (const float*)d_in[6];
    const float* lin_W   = (const float*)d_in[7];
    const float* lin_b   = (const float*)d_in[8];
    const float* conv_W  = (const float*)d_in[9];
    const float* bias    = (const float*)d_in[10];
    const float* cls_W   = (const float*)d_in[11];
    const float* cls_b   = (const float*)d_in[12];

    char* ws = (char*)d_ws;
    size_t off = 0;
    auto alloc = [&](size_t bytes) -> void* {
        void* p = ws + off;
        off += (bytes + 255) & ~(size_t)255;
        return p;
    };
    __bf16* c      = (__bf16*)alloc((size_t)N_NODES * 256 * 2);       // 51.2 MB
    int4*   bucket = (int4*)alloc((size_t)N_NODES * BCAP * 16);       // 102.4 MB
    float*  proj_a = (float*)alloc((size_t)N_NODES * 4 * 4);
    float*  proj_b = (float*)alloc((size_t)N_NODES * 4 * 4);
    __bf16* Mbf    = (__bf16*)alloc(65536 * 2);
    __bf16* W1bf   = (__bf16*)alloc(4096 * 2);
    float*  dvec   = (float*)alloc(256 * 4);
    int*    deg    = (int*)alloc((size_t)N_NODES * 4);

    float* out_h = (float*)d_out;
    float* out_l = out_h + (size_t)N_NODES * 256;

    hipLaunchKernelGGL(k_init, dim3(663), dim3(256), 0, stream,
                       deg, lin_W, lin_b, conv_W, Mbf, dvec, asg_W1, W1bf);
    hipLaunchKernelGGL(k_gemm, dim3((N_NODES + 127) / 128), dim3(256), 0, stream,
                       x, (const __bf16*)Mbf, (const __bf16*)W1bf, dvec, c, proj_a, proj_b);
    hipLaunchKernelGGL(k_edge, dim3(N_EDGES / 256), dim3(256), 0, stream,
                       row_raw, col_raw, proj_a, proj_b, asg_b1, asg_W2, asg_b2,
                       deg, bucket);
    hipLaunchKernelGGL(k_node, dim3(N_NODES / 4), dim3(256), 0, stream,
                       c, deg, bucket, bias, cls_W, cls_b, out_h, out_l);
}

// Round 4
// 500.564 us; speedup vs baseline: 1.2369x; 1.0638x over previous
//
#include <hip/hip_runtime.h>
#include <hip/hip_bf16.h>

#define N_NODES 100000
#define N_EDGES 1600000
#define BCAP    64          // bucket capacity per node (max degree; Poisson(16) tail ~1e-20)
#define EPS     1e-12f

typedef __bf16 bf16x8 __attribute__((ext_vector_type(8)));
typedef float  f32x4  __attribute__((ext_vector_type(4)));

__device__ __forceinline__ unsigned short f2bf(float f){
    union { float f; unsigned int i; } v; v.f = f;
    unsigned int x = v.i;
    return (unsigned short)((x + 0x7fffu + ((x >> 16) & 1u)) >> 16);
}
__device__ __forceinline__ float bits2f(unsigned int u){
    union { unsigned int i; float f; } v; v.i = u; return v.f;
}

// ---- K_init: blocks [0,390] zero deg; [391,646] fuse M/dvec; [647,662] W1 tile
__global__ void k_init(int* __restrict__ deg,
                       const float* __restrict__ lin_W,
                       const float* __restrict__ lin_b,
                       const float* __restrict__ conv_W,
                       __bf16* __restrict__ Mbf,
                       float* __restrict__ dvec,
                       const float* __restrict__ asg_W1,
                       __bf16* __restrict__ W1bf){
    int b = blockIdx.x;
    int t = threadIdx.x;
    if (b < 391){
        int i = b * 256 + t;
        if (i < N_NODES) deg[i] = 0;
    } else if (b < 647){
        int id = (b - 391) * 256 + t;             // 0..65535
        int f  = id & 255;
        int o  = id >> 8;                          // k*64+q
        int k  = o >> 6;
        const float* cw = conv_W + o * 64;         // conv_W[k][q][p]
        const float* lw = lin_W + k * 64 * 256 + f;// lin_W[k][p][f]
        float s = 0.f;
        #pragma unroll 8
        for (int p = 0; p < 64; ++p) s += cw[p] * lw[p * 256];
        Mbf[id] = (__bf16)s;
        if (f == 0){
            const float* lb = lin_b + k * 64;
            float d = 0.f;
            for (int p = 0; p < 64; ++p) d += lb[p] * cw[p];
            dvec[o] = d;
        }
    } else {
        int id = (b - 647) * 256 + t;              // 0..4095
        int f  = id & 255;
        int o  = id >> 8;                          // 0..15
        float v = 0.f;
        if (o < 4)      v = asg_W1[o * 512 + f];
        else if (o < 8) v = asg_W1[(o - 4) * 512 + 256 + f];
        W1bf[id] = (__bf16)v;
    }
}

// ---- K_gemm v2: 2(M)x2(N) wave grid per block; wave = 32 nodes x 128 outs.
// acc = 64 regs/lane (was 128) -> ~3-4 waves/SIMD instead of 1 (occupancy fix).
__global__ __launch_bounds__(256) void k_gemm(const float* __restrict__ x,
                                              const __bf16* __restrict__ Mbf,
                                              const __bf16* __restrict__ W1bf,
                                              const float* __restrict__ dvec,
                                              __bf16* __restrict__ c,
                                              float* __restrict__ proj_a,
                                              float* __restrict__ proj_b){
    int lane = threadIdx.x & 63, wv = threadIdx.x >> 6;
    int wm = wv & 1, wn = wv >> 1;
    int nb = blockIdx.x * 64 + wm * 32;    // 32 nodes per wave
    int ob = wn * 128;                     // output half per wave
    int l15 = lane & 15, quad = lane >> 4;
    f32x4 acc[2][8], accp[2];
    #pragma unroll
    for (int mi = 0; mi < 2; ++mi){
        accp[mi] = f32x4{0.f, 0.f, 0.f, 0.f};
        #pragma unroll
        for (int ni = 0; ni < 8; ++ni) acc[mi][ni] = f32x4{0.f, 0.f, 0.f, 0.f};
    }
    const float* xg[2];
    #pragma unroll
    for (int mi = 0; mi < 2; ++mi){
        int row = nb + mi * 16 + l15;
        if (row >= N_NODES) row = N_NODES - 1;   // clamp for tail
        xg[mi] = x + (size_t)row * 256 + quad * 8;
    }
    for (int k0 = 0; k0 < 256; k0 += 32){
        bf16x8 a[2];
        #pragma unroll
        for (int mi = 0; mi < 2; ++mi){
            float4 lo = *(const float4*)(xg[mi] + k0);
            float4 hi = *(const float4*)(xg[mi] + k0 + 4);
            a[mi][0] = (__bf16)lo.x; a[mi][1] = (__bf16)lo.y;
            a[mi][2] = (__bf16)lo.z; a[mi][3] = (__bf16)lo.w;
            a[mi][4] = (__bf16)hi.x; a[mi][5] = (__bf16)hi.y;
            a[mi][6] = (__bf16)hi.z; a[mi][7] = (__bf16)hi.w;
        }
        #pragma unroll
        for (int ni = 0; ni < 8; ++ni){
            bf16x8 b = *(const bf16x8*)(Mbf + (size_t)(ob + ni * 16 + l15) * 256 + k0 + quad * 8);
            acc[0][ni] = __builtin_amdgcn_mfma_f32_16x16x32_bf16(a[0], b, acc[0][ni], 0, 0, 0);
            acc[1][ni] = __builtin_amdgcn_mfma_f32_16x16x32_bf16(a[1], b, acc[1][ni], 0, 0, 0);
        }
        if (wn == 0){
            bf16x8 bw = *(const bf16x8*)(W1bf + (size_t)l15 * 256 + k0 + quad * 8);
            accp[0] = __builtin_amdgcn_mfma_f32_16x16x32_bf16(a[0], bw, accp[0], 0, 0, 0);
            accp[1] = __builtin_amdgcn_mfma_f32_16x16x32_bf16(a[1], bw, accp[1], 0, 0, 0);
        }
    }
    #pragma unroll
    for (int ni = 0; ni < 8; ++ni){
        int o = ob + ni * 16 + l15;
        float dv = dvec[o];
        #pragma unroll
        for (int mi = 0; mi < 2; ++mi){
            int nrow = nb + mi * 16 + quad * 4;
            #pragma unroll
            for (int r = 0; r < 4; ++r){
                int node = nrow + r;
                if (node < N_NODES) c[(size_t)node * 256 + o] = (__bf16)(acc[mi][ni][r] + dv);
            }
        }
    }
    if (wn == 0 && l15 < 8){
        #pragma unroll
        for (int mi = 0; mi < 2; ++mi){
            int nrow = nb + mi * 16 + quad * 4;
            #pragma unroll
            for (int r = 0; r < 4; ++r){
                int node = nrow + r;
                if (node < N_NODES){
                    float v = accp[mi][r];
                    if (l15 < 4) proj_a[node * 4 + l15] = v;
                    else         proj_b[node * 4 + (l15 - 4)] = v;
                }
            }
        }
    }
}

// ---- K_edge: local dtype detect + softmax gate + bucket scatter {col, w*4 bf16}
__global__ __launch_bounds__(256) void k_edge(const void* __restrict__ row_raw,
                                              const void* __restrict__ col_raw,
                                              const float* __restrict__ proj_a,
                                              const float* __restrict__ proj_b,
                                              const float* __restrict__ asg_b1,
                                              const float* __restrict__ asg_W2,
                                              const float* __restrict__ asg_b2,
                                              int* __restrict__ deg,
                                              int4* __restrict__ bucket){
    __shared__ int s_is64;
    int t = threadIdx.x;
    if (t == 0) s_is64 = 1;
    __syncthreads();
    // sample the first 512 words of both arrays: int64 inputs have all odd words 0
    unsigned v = ((const unsigned*)row_raw)[2 * t + 1] | ((const unsigned*)col_raw)[2 * t + 1];
    if (v) s_is64 = 0;
    __syncthreads();

    int e = blockIdx.x * 256 + t;
    if (e >= N_EDGES) return;
    int r, cl;
    if (s_is64){
        r  = (int)((const long long*)row_raw)[e];
        cl = (int)((const long long*)col_raw)[e];
    } else {
        r  = ((const int*)row_raw)[e];
        cl = ((const int*)col_raw)[e];
    }
    float4 pa = *(const float4*)(proj_a + (size_t)cl * 4);
    float4 pb = *(const float4*)(proj_b + (size_t)r * 4);
    float h1[4];
    h1[0] = pa.x + pb.x + asg_b1[0];
    h1[1] = pa.y + pb.y + asg_b1[1];
    h1[2] = pa.z + pb.z + asg_b1[2];
    h1[3] = pa.w + pb.w + asg_b1[3];
    float h2[4];
    #pragma unroll
    for (int i = 0; i < 4; ++i){
        float s = asg_b2[i];
        #pragma unroll
        for (int j = 0; j < 4; ++j) s += asg_W2[i * 4 + j] * h1[j];
        h2[i] = s;
    }
    float m = fmaxf(fmaxf(h2[0], h2[1]), fmaxf(h2[2], h2[3]));
    float e0 = __expf(h2[0] - m), e1 = __expf(h2[1] - m);
    float e2 = __expf(h2[2] - m), e3 = __expf(h2[3] - m);
    float inv = 1.f / (e0 + e1 + e2 + e3);
    unsigned b0 = f2bf(e0 * inv), b1 = f2bf(e1 * inv);
    unsigned b2 = f2bf(e2 * inv), b3 = f2bf(e3 * inv);
    int4 rec;
    rec.x = cl;
    rec.y = (int)(b0 | (b1 << 16));
    rec.z = (int)(b2 | (b3 << 16));
    rec.w = 0;
    int pos = atomicAdd(&deg[r], 1);
    if (pos < BCAP) bucket[(size_t)r * BCAP + pos] = rec;
}

// ---- K_node v2: ONE WAVE PER NODE. Zero barriers, zero LDS.
__global__ __launch_bounds__(256) void k_node(const __bf16* __restrict__ c,
                                              const int* __restrict__ deg,
                                              const int4* __restrict__ bucket,
                                              const float* __restrict__ bias,
                                              const float* __restrict__ cls_W,
                                              const float* __restrict__ cls_b,
                                              float* __restrict__ out_h,
                                              float* __restrict__ out_logits){
    int wv = __builtin_amdgcn_readfirstlane((int)(threadIdx.x >> 6));
    int l  = threadIdx.x & 63;
    int n  = blockIdx.x * 4 + wv;
    int k2 = l >> 4;

    // per-lane constants (L1/L2-resident)
    float4 bi = *(const float4*)(bias  + l * 4);
    float4 w0 = *(const float4*)(cls_W + 0 * 256 + l * 4);
    float4 w1 = *(const float4*)(cls_W + 1 * 256 + l * 4);
    float4 w2 = *(const float4*)(cls_W + 2 * 256 + l * 4);
    float4 w3 = *(const float4*)(cls_W + 3 * 256 + l * 4);

    int dn = deg[n]; if (dn > BCAP) dn = BCAP;
    const int4* rec = bucket + (size_t)n * BCAP;
    const __bf16* cb = c + (size_t)l * 4;

    bool hi2 = (k2 & 2) != 0;    // use rec.z (k=2,3) vs rec.y (k=0,1)
    bool odd = (k2 & 1) != 0;    // use hi16 vs lo16

    float a0 = 0.f, a1 = 0.f, a2 = 0.f, a3 = 0.f;
    #pragma unroll 4
    for (int i = 0; i < dn; ++i){
        int4 rc = rec[i];                         // wave-uniform -> s_load
        int  ww = hi2 ? rc.z : rc.y;
        unsigned wb = odd ? ((unsigned)ww & 0xffff0000u) : ((unsigned)ww << 16);
        float w = bits2f(wb);
        uint2 vv = *(const uint2*)(cb + (size_t)rc.x * 256);   // 8B/lane, 512B/wave
        a0 += w * bits2f(vv.x << 16);
        a1 += w * bits2f(vv.x & 0xffff0000u);
        a2 += w * bits2f(vv.y << 16);
        a3 += w * bits2f(vv.y & 0xffff0000u);
    }
    a0 += bi.x; a1 += bi.y; a2 += bi.z; a3 += bi.w;

    // norm over each 64-feature group = 16 consecutive lanes
    float ss = a0 * a0 + a1 * a1 + a2 * a2 + a3 * a3;
    ss += __shfl_xor(ss, 1);
    ss += __shfl_xor(ss, 2);
    ss += __shfl_xor(ss, 4);
    ss += __shfl_xor(ss, 8);
    float nrm = fmaxf(sqrtf(ss), EPS);
    float h0 = a0 / nrm, h1 = a1 / nrm, h2 = a2 / nrm, h3 = a3 / nrm;
    *(float4*)(out_h + (size_t)n * 256 + l * 4) = make_float4(h0, h1, h2, h3);

    // logits: per-lane partial dot then full-wave butterfly
    float p0 = h0 * w0.x + h1 * w0.y + h2 * w0.z + h3 * w0.w;
    float p1 = h0 * w1.x + h1 * w1.y + h2 * w1.z + h3 * w1.w;
    float p2 = h0 * w2.x + h1 * w2.y + h2 * w2.z + h3 * w2.w;
    float p3 = h0 * w3.x + h1 * w3.y + h2 * w3.z + h3 * w3.w;
    #pragma unroll
    for (int off = 1; off < 64; off <<= 1){
        p0 += __shfl_xor(p0, off);
        p1 += __shfl_xor(p1, off);
        p2 += __shfl_xor(p2, off);
        p3 += __shfl_xor(p3, off);
    }
    if (l == 0){
        float4 lg = make_float4(p0 + cls_b[0], p1 + cls_b[1],
                                p2 + cls_b[2], p3 + cls_b[3]);
        *(float4*)(out_logits + (size_t)n * 4) = lg;
    }
}

extern "C" void kernel_launch(void* const* d_in, const int* in_sizes, int n_in,
                              void* d_out, int out_size, void* d_ws, size_t ws_size,
                              hipStream_t stream){
    const float* x       = (const float*)d_in[0];
    const void*  row_raw = d_in[1];
    const void*  col_raw = d_in[2];
    const float* asg_W1  = (const float*)d_in[3];
    const float* asg_b1  = (const float*)d_in[4];
    const float* asg_W2  = (const float*)d_in[5];
    const float* asg_b2  = (const float*)d_in[6];
    const float* lin_W   = (const float*)d_in[7];
    const float* lin_b   = (const float*)d_in[8];
    const float* conv_W  = (const float*)d_in[9];
    const float* bias    = (const float*)d_in[10];
    const float* cls_W   = (const float*)d_in[11];
    const float* cls_b   = (const float*)d_in[12];

    char* ws = (char*)d_ws;
    size_t off = 0;
    auto alloc = [&](size_t bytes) -> void* {
        void* p = ws + off;
        off += (bytes + 255) & ~(size_t)255;
        return p;
    };
    __bf16* c      = (__bf16*)alloc((size_t)N_NODES * 256 * 2);       // 51.2 MB
    int4*   bucket = (int4*)alloc((size_t)N_NODES * BCAP * 16);       // 102.4 MB
    float*  proj_a = (float*)alloc((size_t)N_NODES * 4 * 4);
    float*  proj_b = (float*)alloc((size_t)N_NODES * 4 * 4);
    __bf16* Mbf    = (__bf16*)alloc(65536 * 2);
    __bf16* W1bf   = (__bf16*)alloc(4096 * 2);
    float*  dvec   = (float*)alloc(256 * 4);
    int*    deg    = (int*)alloc((size_t)N_NODES * 4);

    float* out_h = (float*)d_out;
    float* out_l = out_h + (size_t)N_NODES * 256;

    hipLaunchKernelGGL(k_init, dim3(663), dim3(256), 0, stream,
                       deg, lin_W, lin_b, conv_W, Mbf, dvec, asg_W1, W1bf);
    hipLaunchKernelGGL(k_gemm, dim3((N_NODES + 63) / 64), dim3(256), 0, stream,
                       x, (const __bf16*)Mbf, (const __bf16*)W1bf, dvec, c, proj_a, proj_b);
    hipLaunchKernelGGL(k_edge, dim3(N_EDGES / 256), dim3(256), 0, stream,
                       row_raw, col_raw, proj_a, proj_b, asg_b1, asg_W2, asg_b2,
                       deg, bucket);
    hipLaunchKernelGGL(k_node, dim3(N_NODES / 4), dim3(256), 0, stream,
                       c, deg, bucket, bias, cls_W, cls_b, out_h, out_l);
}